// Round 16
// baseline (66.415 us; speedup 1.0000x reference)
//
#include <hip/hip_runtime.h>

#ifndef __has_builtin
#define __has_builtin(x) 0
#endif

#if __has_builtin(__builtin_amdgcn_logf)
__device__ __forceinline__ float flog2(float x) { return __builtin_amdgcn_logf(x); }
#else
__device__ __forceinline__ float flog2(float x) { return log2f(x); }
#endif
#if __has_builtin(__builtin_amdgcn_exp2f)
__device__ __forceinline__ float fexp2(float x) { return __builtin_amdgcn_exp2f(x); }
#else
__device__ __forceinline__ float fexp2(float x) { return exp2f(x); }
#endif

#define L2E 1.4426950408889634f   // log2(e)
#define LN2 0.6931471805599453
#define BIGL (1.0e10f * L2E)

template <int CTRL, int RM, int BM>
__device__ __forceinline__ float dpp_f(float v, float old) {
  int r = __builtin_amdgcn_update_dpp(__builtin_bit_cast(int, old),
                                      __builtin_bit_cast(int, v),
                                      CTRL, RM, BM, false);
  return __builtin_bit_cast(float, r);
}

// lane i <- lane i-1; lane 0 <- 0. fp64 via DPP on both halves.
__device__ __forceinline__ double shup1z_d(double v) {
  int lo = __double2loint(v), hi = __double2hiint(v);
  int lo2 = __builtin_amdgcn_update_dpp(0, lo, 0x138, 0xF, 0xF, false);
  int hi2 = __builtin_amdgcn_update_dpp(0, hi, 0x138, 0xF, 0xF, false);
  return __hiloint2double(hi2, lo2);
}

// wave max -> lane 63 (nonnegative floats)
__device__ __forceinline__ float wave_max63(float m) {
  m = fmaxf(m, dpp_f<0x111, 0xF, 0xF>(m, m));  // row_shr:1
  m = fmaxf(m, dpp_f<0x112, 0xF, 0xF>(m, m));  // row_shr:2
  m = fmaxf(m, dpp_f<0x114, 0xF, 0xF>(m, m));  // row_shr:4
  m = fmaxf(m, dpp_f<0x118, 0xF, 0xF>(m, m));  // row_shr:8
  m = fmaxf(m, dpp_f<0x142, 0xA, 0xF>(m, m));  // row_bcast15 -> rows 1,3
  m = fmaxf(m, dpp_f<0x143, 0xC, 0xF>(m, m));  // row_bcast31 -> rows 2,3
  return m;
}

__device__ __forceinline__ unsigned rne_bf16(float f) {
  unsigned kb = __builtin_bit_cast(unsigned, f);
  return (kb + 0x7FFFu + ((kb >> 16) & 1u)) >> 16;
}
__device__ __forceinline__ float bfi(unsigned hw) {
  return __builtin_bit_cast(float, hw << 16);
}

// ---------------- prep: fused-round coefficients, bf16 ----------------------
// Round Q pairs diags (2Q, 2Q+1). Per (Q, lane tt, r): i = 4tt+r,
//   W0 word r = Kd(i) | Kdp1(i)<<16          (Kd = K(2Q,i), Kdp1 = K(2Q+1,i))
//   W1 word r = P1(i) | P2(i)<<16            (P1 = Kdp1(i)*Kd(i-1), P2 = Kdp1(i)*Kd(i))
// uint4 index: b*32768 + Q*128 + w*64 + tt.  Invalid cells have K=0 -> coeffs 0.
__global__ __launch_bounds__(256) void softdtw_prep(
    const float* __restrict__ x, const float* __restrict__ y,
    uint4* __restrict__ Kp4, int B)
{
  const int b  = blockIdx.x % B;            // XCD-aligned with dp block b
  const int K0 = (blockIdx.x / B) << 6;
  const int i0 = threadIdx.x;               // 0..255

  __shared__ __align__(16) unsigned short tileK[64][256];   // [kkL][row]

  const float* xb = x + ((size_t)b * 256 + i0) * 8;
  float4 xa = *(const float4*)(xb);
  float4 xc = *(const float4*)(xb + 4);
  const float* yb = y + (size_t)b * 256 * 8;

  for (int jj = 0; jj < 64; ++jj) {
    int j0 = K0 + jj - i0;
    bool valid = (unsigned)j0 < 256u;
    int jc = j0 < 0 ? 0 : (j0 > 255 ? 255 : j0);
    const float4* yp = (const float4*)(yb + jc * 8);
    float4 ya = yp[0], yc = yp[1];
    float d, D;
    d = xa.x - ya.x; D = d * d;
    d = xa.y - ya.y; D = fmaf(d, d, D);
    d = xa.z - ya.z; D = fmaf(d, d, D);
    d = xa.w - ya.w; D = fmaf(d, d, D);
    d = xc.x - yc.x; D = fmaf(d, d, D);
    d = xc.y - yc.y; D = fmaf(d, d, D);
    d = xc.z - yc.z; D = fmaf(d, d, D);
    d = xc.w - yc.w; D = fmaf(d, d, D);
    float K = valid ? fexp2(-L2E * D) : 0.0f;
    tileK[jj][i0] = (unsigned short)rne_bf16(K);
  }
  __syncthreads();

  // pack pass: 4096 uint4 per block; o = tid + k*256 (w uniform per wave)
  const size_t obase4 = (size_t)b * 32768;
  #pragma unroll 1
  for (int k = 0; k < 16; ++k) {
    int o = threadIdx.x + (k << 8);        // 0..4095
    int qL = o >> 7;                        // local round 0..31
    int w  = (o >> 6) & 1;
    int tt = o & 63;
    int ib = 4 * tt;
    uint4 v;
    if (w == 0) {
      v.x = (unsigned)tileK[2*qL][ib+0] | ((unsigned)tileK[2*qL+1][ib+0] << 16);
      v.y = (unsigned)tileK[2*qL][ib+1] | ((unsigned)tileK[2*qL+1][ib+1] << 16);
      v.z = (unsigned)tileK[2*qL][ib+2] | ((unsigned)tileK[2*qL+1][ib+2] << 16);
      v.w = (unsigned)tileK[2*qL][ib+3] | ((unsigned)tileK[2*qL+1][ib+3] << 16);
    } else {
      unsigned r_[4];
      #pragma unroll
      for (int r = 0; r < 4; ++r) {
        int i = ib + r;
        unsigned kd  = tileK[2*qL][i];
        unsigned kdp = tileK[2*qL+1][i];
        unsigned kdm = (i == 0) ? 0u : (unsigned)tileK[2*qL][i-1];
        float p1 = bfi(kdp) * bfi(kdm);
        float p2 = bfi(kdp) * bfi(kd);
        r_[r] = rne_bf16(p1) | (rne_bf16(p2) << 16);
      }
      v.x = r_[0]; v.y = r_[1]; v.z = r_[2]; v.w = r_[3];
    }
    Kp4[obase4 + (size_t)((K0 >> 1) + qL) * 128 + (size_t)w * 64 + tt] = v;
  }
}

// ---------------- DP: fused 2-diagonal rounds, f64 common-scale -------------
// State: E1 = diag d-1, E2 = diag d-2. Round: T(i) = E1(i-1)+E1(i)+E2(i-1);
// newE2 = Kd*T; newE1 = P1*T(i-1) + P2*T(i) + Kdp1*E1(i-1). 256 rounds vs 511
// steps: halves the serial-dependency rounds (the measured ~155cyc/step fixed
// cost). RENORM every 8 rounds = 16 diags (R15-verified cadence/target).
// Corner: shE2 := 1 at (t==0, round 0) (diag -2). Borders via K = 0.
__global__ __launch_bounds__(64) void softdtw_dp(
    const uint4* __restrict__ Kp4, float* __restrict__ out)
{
  const int b = blockIdx.x;
  const int t = threadIdx.x;

  const char* kbase = (const char*)(Kp4 + (size_t)b * 32768) + t * 16;

  double E1[4] = {0.0, 0.0, 0.0, 0.0};   // diag d-1
  double E2[4] = {0.0, 0.0, 0.0, 0.0};   // diag d-2
  int Csum = 0;

#define CVTLO(u) ((double)__builtin_bit_cast(float, (u) << 16))
#define CVTHI(u) ((double)__builtin_bit_cast(float, (u) & 0xFFFF0000u))

#define ROUND(W0_, W1_, FIRSTF) do {                                          \
    double Kd0 = CVTLO((W0_).x), Kp0 = CVTHI((W0_).x);                        \
    double Kd1 = CVTLO((W0_).y), Kp1 = CVTHI((W0_).y);                        \
    double Kd2 = CVTLO((W0_).z), Kp2 = CVTHI((W0_).z);                        \
    double Kd3 = CVTLO((W0_).w), Kp3 = CVTHI((W0_).w);                        \
    double P10 = CVTLO((W1_).x), P20 = CVTHI((W1_).x);                        \
    double P11 = CVTLO((W1_).y), P21 = CVTHI((W1_).y);                        \
    double P12 = CVTLO((W1_).z), P22 = CVTHI((W1_).z);                        \
    double P13 = CVTLO((W1_).w), P23 = CVTHI((W1_).w);                        \
    double shE1 = shup1z_d(E1[3]);                                            \
    double shE2 = shup1z_d(E2[3]);                                            \
    if (FIRSTF) shE2 = (t == 0) ? 1.0 : shE2;                                 \
    double T0 = (shE1 + E1[0]) + shE2;                                        \
    double T1 = (E1[0] + E1[1]) + E2[0];                                      \
    double T2 = (E1[1] + E1[2]) + E2[1];                                      \
    double T3 = (E1[2] + E1[3]) + E2[2];                                      \
    double shT = shup1z_d(T3);                                                \
    double m0 = fma(P20, T0, Kp0 * shE1);                                     \
    double m1 = fma(P21, T1, Kp1 * E1[0]);                                    \
    double m2 = fma(P22, T2, Kp2 * E1[1]);                                    \
    double m3 = fma(P23, T3, Kp3 * E1[2]);                                    \
    E2[0] = Kd0 * T0; E2[1] = Kd1 * T1;                                       \
    E2[2] = Kd2 * T2; E2[3] = Kd3 * T3;                                       \
    E1[0] = fma(P10, shT, m0);                                                \
    E1[1] = fma(P11, T0, m1);                                                 \
    E1[2] = fma(P12, T1, m2);                                                 \
    E1[3] = fma(P13, T2, m3);                                                 \
  } while (0)

#define RENORM() do {                                                         \
    double m4_ = fmax(fmax(E1[0], E1[1]), fmax(E1[2], E1[3]));                \
    float mh_ = __builtin_bit_cast(float, __double2hiint(m4_));               \
    mh_ = wave_max63(mh_);                                                    \
    int mb_ = __builtin_amdgcn_readlane(__builtin_bit_cast(int, mh_), 63);    \
    int s_ = (mb_ == 0) ? 0 : (1823 - ((mb_ >> 20) & 0x7FF));                 \
    E1[0] = ldexp(E1[0], s_); E1[1] = ldexp(E1[1], s_);                       \
    E1[2] = ldexp(E1[2], s_); E1[3] = ldexp(E1[3], s_);                       \
    E2[0] = ldexp(E2[0], s_); E2[1] = ldexp(E2[1], s_);                       \
    E2[2] = ldexp(E2[2], s_); E2[3] = ldexp(E2[3], s_);                       \
    Csum += s_;                                                               \
  } while (0)

  // one 8-round chunk (16 diagonals): load next chunk's 16 uint4, compute 8
  // fused rounds from CB, renorm once.
#define CHUNK8(CB, LB, FIRSTF) do {                                           \
    LB[0]  = *(const uint4*)(kbase);                                          \
    LB[1]  = *(const uint4*)(kbase + 1024);                                   \
    LB[2]  = *(const uint4*)(kbase + 2048);                                   \
    LB[3]  = *(const uint4*)(kbase + 3072);                                   \
    LB[4]  = *(const uint4*)(kbase + 4096);                                   \
    LB[5]  = *(const uint4*)(kbase + 5120);                                   \
    LB[6]  = *(const uint4*)(kbase + 6144);                                   \
    LB[7]  = *(const uint4*)(kbase + 7168);                                   \
    LB[8]  = *(const uint4*)(kbase + 8192);                                   \
    LB[9]  = *(const uint4*)(kbase + 9216);                                   \
    LB[10] = *(const uint4*)(kbase + 10240);                                  \
    LB[11] = *(const uint4*)(kbase + 11264);                                  \
    LB[12] = *(const uint4*)(kbase + 12288);                                  \
    LB[13] = *(const uint4*)(kbase + 13312);                                  \
    LB[14] = *(const uint4*)(kbase + 14336);                                  \
    LB[15] = *(const uint4*)(kbase + 15360);                                  \
    kbase += 16384;                                                           \
    __builtin_amdgcn_sched_barrier(0);                                        \
    ROUND(CB[0],  CB[1],  FIRSTF);                                            \
    ROUND(CB[2],  CB[3],  false);                                             \
    ROUND(CB[4],  CB[5],  false);                                             \
    ROUND(CB[6],  CB[7],  false);                                             \
    ROUND(CB[8],  CB[9],  false);                                             \
    ROUND(CB[10], CB[11], false);                                             \
    ROUND(CB[12], CB[13], false);                                             \
    ROUND(CB[14], CB[15], false);                                             \
    RENORM();                                                                 \
  } while (0)

  uint4 KA[16], KB[16];
  #pragma unroll
  for (int q = 0; q < 16; ++q)
    KA[q] = *(const uint4*)(kbase + q * 1024);
  kbase += 16384;

  CHUNK8(KA, KB, true);             // chunk 0 (rounds 0..7), loads chunk 1
  #pragma unroll 1
  for (int c = 0; c < 15; ++c) {    // chunks 1..30 (rounds 8..247)
    CHUNK8(KB, KA, false);
    CHUNK8(KA, KB, false);
  }
  // tail: chunk 31 in KB = rounds 248..255. 7 full rounds (diags 496..509):
  ROUND(KB[0],  KB[1],  false);
  ROUND(KB[2],  KB[3],  false);
  ROUND(KB[4],  KB[5],  false);
  ROUND(KB[6],  KB[7],  false);
  ROUND(KB[8],  KB[9],  false);
  ROUND(KB[10], KB[11], false);
  ROUND(KB[12], KB[13], false);
  // final single diagonal 510: E = K_510(i)*T(i); answer cell is lane 63 r=3,
  // whose T3 = E1[2]+E1[3]+E2[2] is lane-local (no shuffle needed).
  if (t == 63) {
    double Kd3 = CVTLO(KB[14].w);           // round 255 W0, r=3 -> K(510, 255)
    double T3 = (E1[2] + E1[3]) + E2[2];
    double E = Kd3 * T3;
    int ex;
    double mant = frexp(E, &ex);            // mant in [0.5, 1)
    float l2 = (float)ex + flog2((float)mant);
    out[b] = (float)(LN2 * ((double)Csum - (double)l2));
  }
}

// ---------------- fallback (R1 log-domain kernel), used if ws too small -----
__global__ __launch_bounds__(64) void softdtw_fallback(
    const float* __restrict__ x, const float* __restrict__ y,
    float* __restrict__ out)
{
  const int b = blockIdx.x;
  const int t = threadIdx.x;
  __shared__ float zbuf[4][64][9];
  const float* xb = x + (size_t)b * 256 * 8;
  const float* yb = y + (size_t)b * 256 * 8;
  float xe[4][9];
  float x2L[4];
  #pragma unroll
  for (int r = 0; r < 4; ++r) {
    const int row = 4 * t + r;
    float4 a = *(const float4*)(yb + row * 8);
    float4 c = *(const float4*)(yb + row * 8 + 4);
    float y2 = a.x*a.x + a.y*a.y + a.z*a.z + a.w*a.w
             + c.x*c.x + c.y*c.y + c.z*c.z + c.w*c.w;
    float* zr = &zbuf[r][t][0];
    zr[0] = -2.0f*L2E*a.x; zr[1] = -2.0f*L2E*a.y; zr[2] = -2.0f*L2E*a.z; zr[3] = -2.0f*L2E*a.w;
    zr[4] = -2.0f*L2E*c.x; zr[5] = -2.0f*L2E*c.y; zr[6] = -2.0f*L2E*c.z; zr[7] = -2.0f*L2E*c.w;
    zr[8] = L2E * y2;
    float4 xa = *(const float4*)(xb + row * 8);
    float4 xc = *(const float4*)(xb + row * 8 + 4);
    xe[r][0]=xa.x; xe[r][1]=xa.y; xe[r][2]=xa.z; xe[r][3]=xa.w;
    xe[r][4]=xc.x; xe[r][5]=xc.y; xe[r][6]=xc.z; xe[r][7]=xc.w; xe[r][8]=1.0f;
    x2L[r] = L2E*(xa.x*xa.x + xa.y*xa.y + xa.z*xa.z + xa.w*xa.w
                + xc.x*xc.x + xc.y*xc.y + xc.z*xc.z + xc.w*xc.w);
  }
  __syncthreads();
  float zA[9], zB[9], zC[9], zD[9];
  #pragma unroll
  for (int w = 0; w < 9; ++w) { zA[w]=0.f; zB[w]=0.f; zC[w]=0.f; zD[w]=0.f; }
  float RA[4] = {BIGL,BIGL,BIGL,BIGL};
  float RB[4] = {BIGL,BIGL,BIGL,BIGL};
  int u = -4 * t;
  auto ROWF = [&](int r, float a, float bb, float c, const float (&zr)[9]) -> float {
    float acc = x2L[r];
    #pragma unroll
    for (int d = 0; d < 9; ++d) acc = fmaf(xe[r][d], zr[d], acc);
    float m = fminf(fminf(a, bb), c);
    float e = fexp2(m-a) + fexp2(m-bb) + fexp2(m-c);
    float val = acc + (m - flog2(e));
    return ((unsigned)(u - r) < 256u) ? val : BIGL;
  };
  auto STEP = [&](float (&zw)[9], const float (&zx)[9], const float (&zy)[9],
                  const float (&zz)[9], float (&Rm2)[4], float (&Rm1)[4],
                  int p, int k) {
    int uc = u < 0 ? 0 : (u > 255 ? 255 : u);
    const float* zp = &zbuf[p][uc >> 2][0];
    #pragma unroll
    for (int w = 0; w < 9; ++w) zw[w] = zp[w];
    float up_in = __shfl_up(Rm1[3], 1);
    float dg_in = __shfl_up(Rm2[3], 1);
    float bval = (k == 2) ? 0.0f : BIGL;
    if (t == 0) { up_in = BIGL; dg_in = bval; }
    float n0 = ROWF(0, dg_in,  up_in,  Rm1[0], zw);
    float n1 = ROWF(1, Rm2[0], Rm1[0], Rm1[1], zx);
    float n2 = ROWF(2, Rm2[1], Rm1[1], Rm1[2], zy);
    float n3 = ROWF(3, Rm2[2], Rm1[2], Rm1[3], zz);
    Rm2[0]=n0; Rm2[1]=n1; Rm2[2]=n2; Rm2[3]=n3;
    u += 1;
  };
  int k = 2;
  for (int mi = 0; mi < 127; ++mi) {
    STEP(zD, zA, zB, zC, RA, RB, 0, k);
    STEP(zC, zD, zA, zB, RB, RA, 1, k + 1);
    STEP(zB, zC, zD, zA, RA, RB, 2, k + 2);
    STEP(zA, zB, zC, zD, RB, RA, 3, k + 3);
    k += 4;
  }
  STEP(zD, zA, zB, zC, RA, RB, 0, k);
  STEP(zC, zD, zA, zB, RB, RA, 1, k + 1);
  STEP(zB, zC, zD, zA, RA, RB, 2, k + 2);
  if (t == 63) out[b] = RA[3] * LN2;
}

extern "C" void kernel_launch(void* const* d_in, const int* in_sizes, int n_in,
                              void* d_out, int out_size, void* d_ws, size_t ws_size,
                              hipStream_t stream) {
  const float* x = (const float*)d_in[0];
  const float* y = (const float*)d_in[1];
  float* out = (float*)d_out;
  const int B = in_sizes[0] / (256 * 8);
  const size_t need = (size_t)B * 524288;   // 256 rounds x 128 uint4 x 16B
  if (ws_size >= need) {
    uint4* Kp4 = (uint4*)d_ws;
    softdtw_prep<<<dim3(B * 8), dim3(256), 0, stream>>>(x, y, Kp4, B);
    softdtw_dp<<<dim3(B), dim3(64), 0, stream>>>(Kp4, out);
  } else {
    softdtw_fallback<<<dim3(B), dim3(64), 0, stream>>>(x, y, out);
  }
}

// Round 17
// 51.116 us; speedup vs baseline: 1.2993x; 1.2993x over previous
//
#include <hip/hip_runtime.h>

#ifndef __has_builtin
#define __has_builtin(x) 0
#endif

#if __has_builtin(__builtin_amdgcn_logf)
__device__ __forceinline__ float flog2(float x) { return __builtin_amdgcn_logf(x); }
#else
__device__ __forceinline__ float flog2(float x) { return log2f(x); }
#endif
#if __has_builtin(__builtin_amdgcn_exp2f)
__device__ __forceinline__ float fexp2(float x) { return __builtin_amdgcn_exp2f(x); }
#else
__device__ __forceinline__ float fexp2(float x) { return exp2f(x); }
#endif

#define L2E 1.4426950408889634f   // log2(e)
#define LN2 0.6931471805599453
#define BIGL (1.0e10f * L2E)

template <int CTRL, int RM, int BM>
__device__ __forceinline__ float dpp_f(float v, float old) {
  int r = __builtin_amdgcn_update_dpp(__builtin_bit_cast(int, old),
                                      __builtin_bit_cast(int, v),
                                      CTRL, RM, BM, false);
  return __builtin_bit_cast(float, r);
}

// lane i <- lane i-1; lane 0 <- 0. fp64 via DPP on both halves.
__device__ __forceinline__ double shup1z_d(double v) {
  int lo = __double2loint(v), hi = __double2hiint(v);
  int lo2 = __builtin_amdgcn_update_dpp(0, lo, 0x138, 0xF, 0xF, false);
  int hi2 = __builtin_amdgcn_update_dpp(0, hi, 0x138, 0xF, 0xF, false);
  return __hiloint2double(hi2, lo2);
}

// wave max -> lane 63 (nonnegative floats)
__device__ __forceinline__ float wave_max63(float m) {
  m = fmaxf(m, dpp_f<0x111, 0xF, 0xF>(m, m));  // row_shr:1
  m = fmaxf(m, dpp_f<0x112, 0xF, 0xF>(m, m));  // row_shr:2
  m = fmaxf(m, dpp_f<0x114, 0xF, 0xF>(m, m));  // row_shr:4
  m = fmaxf(m, dpp_f<0x118, 0xF, 0xF>(m, m));  // row_shr:8
  m = fmaxf(m, dpp_f<0x142, 0xA, 0xF>(m, m));  // row_bcast15 -> rows 1,3
  m = fmaxf(m, dpp_f<0x143, 0xC, 0xF>(m, m));  // row_bcast31 -> rows 2,3
  return m;
}

// ---------------- prep: K = bf16(exp(-||x_i - y_j||^2)), PAIR-major layout --
// Kp4[b*16384 + kk2*64 + tt] : 16B = lane tt's 4 cells for diag pair
// {2*kk2, 2*kk2+1}. Diag slot 511 = tileK row 63 of last block = zeros.
// (Verbatim the R9/R15 champion prep.)
__global__ __launch_bounds__(256) void softdtw_prep(
    const float* __restrict__ x, const float* __restrict__ y,
    uint4* __restrict__ Kp4, int B)
{
  const int b  = blockIdx.x % B;            // XCD-aligned with dp block b
  const int K0 = (blockIdx.x / B) << 6;
  const int i0 = threadIdx.x;               // 0..255

  __shared__ __align__(16) unsigned short tileK[64][256];   // [kkL][i0]

  const float* xb = x + ((size_t)b * 256 + i0) * 8;
  float4 xa = *(const float4*)(xb);
  float4 xc = *(const float4*)(xb + 4);
  const float* yb = y + (size_t)b * 256 * 8;

  for (int jj = 0; jj < 64; ++jj) {
    int j0 = K0 + jj - i0;
    bool valid = (unsigned)j0 < 256u;
    int jc = j0 < 0 ? 0 : (j0 > 255 ? 255 : j0);
    const float4* yp = (const float4*)(yb + jc * 8);
    float4 ya = yp[0], yc = yp[1];
    float d, D;
    d = xa.x - ya.x; D = d * d;
    d = xa.y - ya.y; D = fmaf(d, d, D);
    d = xa.z - ya.z; D = fmaf(d, d, D);
    d = xa.w - ya.w; D = fmaf(d, d, D);
    d = xc.x - yc.x; D = fmaf(d, d, D);
    d = xc.y - yc.y; D = fmaf(d, d, D);
    d = xc.z - yc.z; D = fmaf(d, d, D);
    d = xc.w - yc.w; D = fmaf(d, d, D);
    float K = valid ? fexp2(-L2E * D) : 0.0f;
    unsigned kb = __builtin_bit_cast(unsigned, K);
    unsigned rn = (kb + 0x7FFFu + ((kb >> 16) & 1u)) >> 16;   // RNE to bf16
    tileK[jj][i0] = (unsigned short)rn;
  }
  __syncthreads();

  const size_t obase4 = (size_t)b * 16384;
  #pragma unroll
  for (int w = 0; w < 8; ++w) {
    int p = threadIdx.x + (w << 8);
    int kkP = p >> 6;
    int tt = p & 63;
    uint2 lo = *(const uint2*)&tileK[kkP * 2][tt * 4];
    uint2 hi = *(const uint2*)&tileK[kkP * 2 + 1][tt * 4];
    uint4 v; v.x = lo.x; v.y = lo.y; v.z = hi.x; v.w = hi.y;
    Kp4[obase4 + (size_t)((K0 >> 1) + kkP) * 64 + tt] = v;
  }
}

// ---------------- DP: f64 common-scale, FMA-shortened dependency chain ------
// Changes vs R15 (issue-neutral, chain-shortening):
//  - V = fma(K, newest_sum, K*oldest): per-cell chain after E1-ready drops
//    from add+add+mul (3 f64 latencies) to add+fma (2); V0's post-DPP chain
//    drops to a single fma (pre-product overlaps the DPP).
//  - RENORM once per 32 steps (EN <= 2^800*3^32 = 2^851; EO <= ~2^944 < 2^1024).
__global__ __launch_bounds__(64) void softdtw_dp(
    const uint4* __restrict__ Kp4, float* __restrict__ out)
{
  const int b = blockIdx.x;
  const int t = threadIdx.x;

  const char* kbase = (const char*)(Kp4 + (size_t)b * 16384) + t * 16;

  double EA[4] = {0.0, 0.0, 0.0, 0.0};
  double EB[4] = {0.0, 0.0, 0.0, 0.0};
  double dgc = 0.0;          // carried: shup(diag s-2 [3]) for the next step
  int Csum = 0;

#define DPSTEP2(KAw, KBw, E2, E1, FIRSTF) do {                                \
    double K0_ = (double)__builtin_bit_cast(float, (KAw) << 16);              \
    double K1_ = (double)__builtin_bit_cast(float, (KAw) & 0xFFFF0000u);      \
    double K2_ = (double)__builtin_bit_cast(float, (KBw) << 16);              \
    double K3_ = (double)__builtin_bit_cast(float, (KBw) & 0xFFFF0000u);      \
    double dg_ = dgc;                                                         \
    if (FIRSTF) dg_ = (t == 0) ? 1.0 : dg_;                                   \
    double pre0_ = K0_ * (dg_ + E1[0]);   /* overlaps the DPP below */        \
    double pre1_ = K1_ * E2[0];           /* E2 is 2 steps old: early */      \
    double pre2_ = K2_ * E2[1];                                               \
    double pre3_ = K3_ * E2[2];                                               \
    double up_ = shup1z_d(E1[3]);                                             \
    double V0_ = fma(K0_, up_,            pre0_);                             \
    double V1_ = fma(K1_, E1[0] + E1[1],  pre1_);                             \
    double V2_ = fma(K2_, E1[1] + E1[2],  pre2_);                             \
    double V3_ = fma(K3_, E1[2] + E1[3],  pre3_);                             \
    dgc = up_;                                                                \
    E2[0] = V0_; E2[1] = V1_; E2[2] = V2_; E2[3] = V3_;                       \
  } while (0)

#define RENORM(EN, EO) do {                                                   \
    double m4_ = fmax(fmax(EN[0], EN[1]), fmax(EN[2], EN[3]));                \
    float mh_ = __builtin_bit_cast(float, __double2hiint(m4_));               \
    mh_ = wave_max63(mh_);                                                    \
    int mb_ = __builtin_amdgcn_readlane(__builtin_bit_cast(int, mh_), 63);    \
    int s_ = (mb_ == 0) ? 0 : (1823 - ((mb_ >> 20) & 0x7FF));                 \
    EN[0] = ldexp(EN[0], s_); EN[1] = ldexp(EN[1], s_);                       \
    EN[2] = ldexp(EN[2], s_); EN[3] = ldexp(EN[3], s_);                       \
    EO[0] = ldexp(EO[0], s_); EO[1] = ldexp(EO[1], s_);                       \
    EO[2] = ldexp(EO[2], s_); EO[3] = ldexp(EO[3], s_);                       \
    dgc = ldexp(dgc, s_);                                                     \
    Csum += s_;                                                               \
  } while (0)

  // one pair (2 steps): even step writes EA, odd writes EB
#define PAIR(U, FIRSTF)                                                       \
    DPSTEP2((U).x, (U).y, EA, EB, FIRSTF);                                    \
    DPSTEP2((U).z, (U).w, EB, EA, false)

  // one 32-step chunk: issue next chunk's 16 loads, compute 16 pairs from CB,
  // RENORM once per chunk (cadence 32; headroom verified in header).
#define CHUNK32(CB, LB, FIRSTF) do {                                          \
    LB[0]  = *(const uint4*)(kbase);                                          \
    LB[1]  = *(const uint4*)(kbase + 1024);                                   \
    LB[2]  = *(const uint4*)(kbase + 2048);                                   \
    LB[3]  = *(const uint4*)(kbase + 3072);                                   \
    LB[4]  = *(const uint4*)(kbase + 4096);                                   \
    LB[5]  = *(const uint4*)(kbase + 5120);                                   \
    LB[6]  = *(const uint4*)(kbase + 6144);                                   \
    LB[7]  = *(const uint4*)(kbase + 7168);                                   \
    LB[8]  = *(const uint4*)(kbase + 8192);                                   \
    LB[9]  = *(const uint4*)(kbase + 9216);                                   \
    LB[10] = *(const uint4*)(kbase + 10240);                                  \
    LB[11] = *(const uint4*)(kbase + 11264);                                  \
    LB[12] = *(const uint4*)(kbase + 12288);                                  \
    LB[13] = *(const uint4*)(kbase + 13312);                                  \
    LB[14] = *(const uint4*)(kbase + 14336);                                  \
    LB[15] = *(const uint4*)(kbase + 15360);                                  \
    kbase += 16384;                                                           \
    __builtin_amdgcn_sched_barrier(0);                                        \
    PAIR(CB[0], FIRSTF); PAIR(CB[1], false);                                  \
    PAIR(CB[2], false);  PAIR(CB[3], false);                                  \
    PAIR(CB[4], false);  PAIR(CB[5], false);                                  \
    PAIR(CB[6], false);  PAIR(CB[7], false);                                  \
    PAIR(CB[8], false);  PAIR(CB[9], false);                                  \
    PAIR(CB[10], false); PAIR(CB[11], false);                                 \
    PAIR(CB[12], false); PAIR(CB[13], false);                                 \
    PAIR(CB[14], false); PAIR(CB[15], false);                                 \
    RENORM(EB, EA);                                                           \
  } while (0)

  uint4 KA[16], KB[16];
  // preload chunk 0 (pairs 0..15)
  #pragma unroll
  for (int q = 0; q < 16; ++q)
    KA[q] = *(const uint4*)(kbase + q * 1024);
  kbase += 16384;

  CHUNK32(KA, KB, true);            // chunk 0 (steps 0..31), loads chunk 1
  #pragma unroll 1
  for (int c = 0; c < 7; ++c) {     // chunks 1..14 (steps 32..479)
    CHUNK32(KB, KA, false);
    CHUNK32(KA, KB, false);
  }
  // tail: steps 480..510 (31 steps) from KB (pairs 240..255), no loads
  PAIR(KB[0], false); PAIR(KB[1], false);
  PAIR(KB[2], false); PAIR(KB[3], false);
  PAIR(KB[4], false); PAIR(KB[5], false);
  PAIR(KB[6], false); PAIR(KB[7], false);
  RENORM(EB, EA);
  PAIR(KB[8], false);  PAIR(KB[9], false);
  PAIR(KB[10], false); PAIR(KB[11], false);
  PAIR(KB[12], false); PAIR(KB[13], false);
  PAIR(KB[14], false);
  DPSTEP2(KB[15].x, KB[15].y, EA, EB, false);  // step 510 -> EA, result EA[3]

  if (t == 63) {
    int ex;
    double mant = frexp(EA[3], &ex);   // mant in [0.5, 1)
    float l2 = (float)ex + flog2((float)mant);
    out[b] = (float)(LN2 * ((double)Csum - (double)l2));
  }
}

// ---------------- fallback (R1 log-domain kernel), used if ws too small -----
__global__ __launch_bounds__(64) void softdtw_fallback(
    const float* __restrict__ x, const float* __restrict__ y,
    float* __restrict__ out)
{
  const int b = blockIdx.x;
  const int t = threadIdx.x;
  __shared__ float zbuf[4][64][9];
  const float* xb = x + (size_t)b * 256 * 8;
  const float* yb = y + (size_t)b * 256 * 8;
  float xe[4][9];
  float x2L[4];
  #pragma unroll
  for (int r = 0; r < 4; ++r) {
    const int row = 4 * t + r;
    float4 a = *(const float4*)(yb + row * 8);
    float4 c = *(const float4*)(yb + row * 8 + 4);
    float y2 = a.x*a.x + a.y*a.y + a.z*a.z + a.w*a.w
             + c.x*c.x + c.y*c.y + c.z*c.z + c.w*c.w;
    float* zr = &zbuf[r][t][0];
    zr[0] = -2.0f*L2E*a.x; zr[1] = -2.0f*L2E*a.y; zr[2] = -2.0f*L2E*a.z; zr[3] = -2.0f*L2E*a.w;
    zr[4] = -2.0f*L2E*c.x; zr[5] = -2.0f*L2E*c.y; zr[6] = -2.0f*L2E*c.z; zr[7] = -2.0f*L2E*c.w;
    zr[8] = L2E * y2;
    float4 xa = *(const float4*)(xb + row * 8);
    float4 xc = *(const float4*)(xb + row * 8 + 4);
    xe[r][0]=xa.x; xe[r][1]=xa.y; xe[r][2]=xa.z; xe[r][3]=xa.w;
    xe[r][4]=xc.x; xe[r][5]=xc.y; xe[r][6]=xc.z; xe[r][7]=xc.w; xe[r][8]=1.0f;
    x2L[r] = L2E*(xa.x*xa.x + xa.y*xa.y + xa.z*xa.z + xa.w*xa.w
                + xc.x*xc.x + xc.y*xc.y + xc.z*xc.z + xc.w*xc.w);
  }
  __syncthreads();
  float zA[9], zB[9], zC[9], zD[9];
  #pragma unroll
  for (int w = 0; w < 9; ++w) { zA[w]=0.f; zB[w]=0.f; zC[w]=0.f; zD[w]=0.f; }
  float RA[4] = {BIGL,BIGL,BIGL,BIGL};
  float RB[4] = {BIGL,BIGL,BIGL,BIGL};
  int u = -4 * t;
  auto ROWF = [&](int r, float a, float bb, float c, const float (&zr)[9]) -> float {
    float acc = x2L[r];
    #pragma unroll
    for (int d = 0; d < 9; ++d) acc = fmaf(xe[r][d], zr[d], acc);
    float m = fminf(fminf(a, bb), c);
    float e = fexp2(m-a) + fexp2(m-bb) + fexp2(m-c);
    float val = acc + (m - flog2(e));
    return ((unsigned)(u - r) < 256u) ? val : BIGL;
  };
  auto STEP = [&](float (&zw)[9], const float (&zx)[9], const float (&zy)[9],
                  const float (&zz)[9], float (&Rm2)[4], float (&Rm1)[4],
                  int p, int k) {
    int uc = u < 0 ? 0 : (u > 255 ? 255 : u);
    const float* zp = &zbuf[p][uc >> 2][0];
    #pragma unroll
    for (int w = 0; w < 9; ++w) zw[w] = zp[w];
    float up_in = __shfl_up(Rm1[3], 1);
    float dg_in = __shfl_up(Rm2[3], 1);
    float bval = (k == 2) ? 0.0f : BIGL;
    if (t == 0) { up_in = BIGL; dg_in = bval; }
    float n0 = ROWF(0, dg_in,  up_in,  Rm1[0], zw);
    float n1 = ROWF(1, Rm2[0], Rm1[0], Rm1[1], zx);
    float n2 = ROWF(2, Rm2[1], Rm1[1], Rm1[2], zy);
    float n3 = ROWF(3, Rm2[2], Rm1[2], Rm1[3], zz);
    Rm2[0]=n0; Rm2[1]=n1; Rm2[2]=n2; Rm2[3]=n3;
    u += 1;
  };
  int k = 2;
  for (int mi = 0; mi < 127; ++mi) {
    STEP(zD, zA, zB, zC, RA, RB, 0, k);
    STEP(zC, zD, zA, zB, RB, RA, 1, k + 1);
    STEP(zB, zC, zD, zA, RA, RB, 2, k + 2);
    STEP(zA, zB, zC, zD, RB, RA, 3, k + 3);
    k += 4;
  }
  STEP(zD, zA, zB, zC, RA, RB, 0, k);
  STEP(zC, zD, zA, zB, RB, RA, 1, k + 1);
  STEP(zB, zC, zD, zA, RA, RB, 2, k + 2);
  if (t == 63) out[b] = RA[3] * LN2;
}

extern "C" void kernel_launch(void* const* d_in, const int* in_sizes, int n_in,
                              void* d_out, int out_size, void* d_ws, size_t ws_size,
                              hipStream_t stream) {
  const float* x = (const float*)d_in[0];
  const float* y = (const float*)d_in[1];
  float* out = (float*)d_out;
  const int B = in_sizes[0] / (256 * 8);
  const size_t need = (size_t)B * 262144;   // 256 diag-pairs x 64 lanes x 16B
  if (ws_size >= need) {
    uint4* Kp4 = (uint4*)d_ws;
    softdtw_prep<<<dim3(B * 8), dim3(256), 0, stream>>>(x, y, Kp4, B);
    softdtw_dp<<<dim3(B), dim3(64), 0, stream>>>(Kp4, out);
  } else {
    softdtw_fallback<<<dim3(B), dim3(64), 0, stream>>>(x, y, out);
  }
}